// Round 8
// baseline (56.830 us; speedup 1.0000x reference)
//
#include <hip/hip_runtime.h>

#define BS 64
#define NQ 300
#define NTGT 1024
#define TT 16
#define MCOL 300
#define NROW 16
#define STR 304
#define BIGF 1000000000.0f

// ---- per-cell cost ----
__device__ __forceinline__ float cell_cost(float p0, float pcx, float pcy, float pw, float ph,
                                           float px1, float py1, float px2, float py2, float parea,
                                           float4 tb)
{
    float cb = fabsf(pcx - tb.x) + fabsf(pcy - tb.y) + fabsf(pw - tb.z) + fabsf(ph - tb.w);
    float tx1 = tb.x - 0.5f*tb.z, ty1 = tb.y - 0.5f*tb.w;
    float tx2 = tb.x + 0.5f*tb.z, ty2 = tb.y + 0.5f*tb.w;
    float tarea = (tx2 - tx1) * (ty2 - ty1);
    float ltx = fmaxf(px1, tx1), lty = fmaxf(py1, ty1);
    float rbx = fminf(px2, tx2), rby = fminf(py2, ty2);
    float iw = fmaxf(rbx - ltx, 0.f), ih = fmaxf(rby - lty, 0.f);
    float inter = iw * ih;
    float uni = parea + tarea - inter;
    float iou = inter * __builtin_amdgcn_rcpf(uni);
    float ex1 = fminf(px1, tx1), ey1 = fminf(py1, ty1);
    float ex2 = fmaxf(px2, tx2), ey2 = fmaxf(py2, ty2);
    float areae = (ex2 - ex1) * (ey2 - ey1);
    float giou = iou - (areae - uni) * __builtin_amdgcn_rcpf(areae);
    return cb - giou - p0;
}

// ================= Kernel 1: cost matrix (lean, own VGPR budget) =================
__global__ __launch_bounds__(256) void cost_kernel(
    const float* __restrict__ logits,
    const float* __restrict__ boxes,
    const float* __restrict__ tgt,
    float* __restrict__ C)
{
    int q = blockIdx.x;                          // 0..19199, uniform per block
    float l0v = logits[2*q], l1v = logits[2*q + 1];
    float p0 = __builtin_amdgcn_rcpf(1.f + __expf(l1v - l0v));   // softmax[0]
    float4 pb = ((const float4*)boxes)[q];
    float px1 = pb.x - 0.5f*pb.z, py1 = pb.y - 0.5f*pb.w;
    float px2 = pb.x + 0.5f*pb.z, py2 = pb.y + 0.5f*pb.w;
    float parea = (px2 - px1) * (py2 - py1);

    int t0 = threadIdx.x << 2;
    const float4* tgt4 = (const float4*)tgt;
    float4 tb0 = tgt4[t0+0], tb1 = tgt4[t0+1], tb2 = tgt4[t0+2], tb3 = tgt4[t0+3];
    float4 r;
    r.x = cell_cost(p0, pb.x, pb.y, pb.z, pb.w, px1, py1, px2, py2, parea, tb0);
    r.y = cell_cost(p0, pb.x, pb.y, pb.z, pb.w, px1, py1, px2, py2, parea, tb1);
    r.z = cell_cost(p0, pb.x, pb.y, pb.z, pb.w, px1, py1, px2, py2, parea, tb2);
    r.w = cell_cost(p0, pb.x, pb.y, pb.z, pb.w, px1, py1, px2, py2, parea, tb3);
    *(float4*)(C + (size_t)q * NTGT + t0) = r;
}

// ---- DPP wave-64 min reductions (result valid in lane 63) ----
template<int CTRL>
__device__ __forceinline__ float dppmin_f(float x) {
    int t = __builtin_amdgcn_update_dpp(__float_as_int(BIGF), __float_as_int(x),
                                        CTRL, 0xF, 0xF, false);
    return fminf(x, __int_as_float(t));
}
template<int CTRL>
__device__ __forceinline__ int dppmin_i(int x) {
    int t = __builtin_amdgcn_update_dpp(0x7FFFFFFF, x, CTRL, 0xF, 0xF, false);
    return (t < x) ? t : x;
}
__device__ __forceinline__ float wave_min_f(float x) {
    x = dppmin_f<0x111>(x);  // row_shr:1
    x = dppmin_f<0x112>(x);  // row_shr:2
    x = dppmin_f<0x114>(x);  // row_shr:4
    x = dppmin_f<0x118>(x);  // row_shr:8
    x = dppmin_f<0x142>(x);  // row_bcast:15
    x = dppmin_f<0x143>(x);  // row_bcast:31
    return x;
}
__device__ __forceinline__ int wave_min_i(int x) {
    x = dppmin_i<0x111>(x);
    x = dppmin_i<0x112>(x);
    x = dppmin_i<0x114>(x);
    x = dppmin_i<0x118>(x);
    x = dppmin_i<0x142>(x);
    x = dppmin_i<0x143>(x);
    return x;
}

// static-index select chain over 5 regs (k0 wave-uniform)
__device__ __forceinline__ int sel5i(const int a[5], int k0) {
    int r = a[0];
    r = (k0 == 1) ? a[1] : r;
    r = (k0 == 2) ? a[2] : r;
    r = (k0 == 3) ? a[3] : r;
    r = (k0 == 4) ? a[4] : r;
    return r;
}

// ================= Kernel 2: Hungarian (JV, warm start), 1 wave / batch =========
__global__ __launch_bounds__(64) void hung_kernel(
    const float* __restrict__ C, float* __restrict__ out)
{
    const int b = blockIdx.x;
    const int lane = threadIdx.x;
    __shared__ float ca[16 * STR + 32];

    // pad slots (j = 301..303 per row, tail) = BIGF; dummy col 0 = 0
    if (lane < 48) ca[(lane / 3) * STR + 301 + (lane % 3)] = BIGF;
    if (lane < 32) ca[16 * STR + lane] = BIGF;
    if (lane < 16) ca[lane * STR] = 0.f;

    // stage this batch's 16x300 block from C (bit-identical to cost_kernel output)
    #pragma unroll
    for (int qi = 0; qi < 5; ++qi) {
        int q = qi * 64 + lane;
        if (q < MCOL) {
            const float4* src = (const float4*)(C + ((size_t)(b*NQ + q)) * NTGT + b*TT);
            float4 a0 = src[0], a1 = src[1], a2 = src[2], a3 = src[3];
            ca[ 0*STR + 1 + q] = a0.x; ca[ 1*STR + 1 + q] = a0.y;
            ca[ 2*STR + 1 + q] = a0.z; ca[ 3*STR + 1 + q] = a0.w;
            ca[ 4*STR + 1 + q] = a1.x; ca[ 5*STR + 1 + q] = a1.y;
            ca[ 6*STR + 1 + q] = a1.z; ca[ 7*STR + 1 + q] = a1.w;
            ca[ 8*STR + 1 + q] = a2.x; ca[ 9*STR + 1 + q] = a2.y;
            ca[10*STR + 1 + q] = a2.z; ca[11*STR + 1 + q] = a2.w;
            ca[12*STR + 1 + q] = a3.x; ca[13*STR + 1 + q] = a3.y;
            ca[14*STR + 1 + q] = a3.z; ca[15*STR + 1 + q] = a3.w;
        }
    }
    __syncthreads();

    // ---- ROW-SIDE warm start: u[i] = rowmin_i (feasible potential; exact optimum) ----
    float u_lane = 0.f;
    #pragma unroll
    for (int t = 0; t < 16; ++t) {
        float loc = BIGF;
        #pragma unroll
        for (int k = 0; k < 5; ++k) {
            int j = lane + (k << 6);
            float c = ca[t*STR + j];
            bool ok = (j >= 1) && (j <= MCOL);
            loc = fminf(loc, ok ? c : BIGF);
        }
        float rm = __int_as_float(
            __builtin_amdgcn_readlane(__float_as_int(wave_min_f(loc)), 63));
        if (lane == t + 1) u_lane = rm;
    }

    int   p_reg[5]   = {0,0,0,0,0};
    int   way_reg[5] = {0,0,0,0,0};
    float vloc[5]    = {0.f,0.f,0.f,0.f,0.f};
    float minv[5];

    for (int i = 1; i <= NROW; ++i) {
        if (lane == 0) p_reg[0] = i;
        unsigned usedm = 0, treemask = 0;
        #pragma unroll
        for (int k = 0; k < 5; ++k) { minv[k] = BIGF; way_reg[k] = 0; }

        int j0 = 0;
        for (;;) {
            int l0 = j0 & 63, k0 = j0 >> 6;            // uniform (SGPR)
            int i0 = __builtin_amdgcn_readlane(sel5i(p_reg, k0), l0);
            if (i0 == 0) break;
            float ui0 = __int_as_float(
                __builtin_amdgcn_readlane(__float_as_int(u_lane), i0));  // u[i0]
            if (lane == l0) usedm |= (1u << k0);
            treemask |= (1u << i0);                     // uniform

            int rowbase = (i0 - 1) * STR + lane;
            float cur[5];
            #pragma unroll
            for (int k = 0; k < 5; ++k) cur[k] = ca[rowbase + (k << 6)];

            float bestv = BIGF; int bestj = 0x7FFFFFFF;
            #pragma unroll
            for (int k = 0; k < 5; ++k) {
                int j = lane + (k << 6);
                bool act = (j <= MCOL);
                bool us  = ((usedm >> k) & 1u) != 0u;
                float cu = cur[k] - ui0 - vloc[k];
                if (act && !us && cu < minv[k]) { minv[k] = cu; way_reg[k] = j0; }
                float mk = (act && !us) ? minv[k] : BIGF;
                if (mk < bestv) { bestv = mk; bestj = j; }  // ascending j per lane
            }
            // wave argmin: DPP value-min, broadcast, then DPP index-min among equals
            float mv = wave_min_f(bestv);
            float delta = __int_as_float(__builtin_amdgcn_readlane(__float_as_int(mv), 63));
            int cand = (bestv == delta) ? bestj : 0x7FFFFFFF;
            int cm = wave_min_i(cand);
            int j1 = __builtin_amdgcn_readlane(cm, 63);

            #pragma unroll
            for (int k = 0; k < 5; ++k) {
                bool us = ((usedm >> k) & 1u) != 0u;
                if (us) { vloc[k] -= delta; }
                else if (lane + (k << 6) <= MCOL) minv[k] -= delta;
            }
            if (lane <= NROW && ((treemask >> lane) & 1u)) u_lane += delta;
            j0 = j1;
        }
        // augment: p[j0] = p[way[j0]] walking back to col 0 (uniform readlanes)
        while (j0 != 0) {
            int l0 = j0 & 63, k0 = j0 >> 6;
            int jn = __builtin_amdgcn_readlane(sel5i(way_reg, k0), l0);
            int pn = __builtin_amdgcn_readlane(sel5i(p_reg, jn >> 6), jn & 63);
            #pragma unroll
            for (int k = 0; k < 5; ++k)
                if (k == k0 && lane == l0) p_reg[k] = pn;
            j0 = jn;
        }
    }

    // ---- extraction: row_ind/col_ind in ascending query order ----
    const size_t ROWB = (size_t)BS * NQ * NTGT;
    const size_t COLB = ROWB + (size_t)BS * TT;
    int base = 0;
    #pragma unroll
    for (int k = 0; k < 5; ++k) {
        int pk1 = (k < 4) ? __shfl(p_reg[k + 1], 0, 64) : 0;   // p[64(k+1)]
        int psh = __shfl(p_reg[k], (lane + 1) & 63, 64);       // p[64k + lane+1]
        int q = (k << 6) | lane;
        int a = (lane == 63) ? pk1 : psh;                      // = p[q+1]
        if (q >= MCOL) a = 0;
        unsigned long long mb = __ballot(a > 0);
        int pos = base + __popcll(mb & ((1ull << lane) - 1ull));
        if (a > 0) {
            out[ROWB + (size_t)b * TT + pos] = (float)q;
            out[COLB + (size_t)b * TT + pos] = (float)(a - 1);
        }
        base += __popcll(mb);
    }
}

extern "C" void kernel_launch(void* const* d_in, const int* in_sizes, int n_in,
                              void* d_out, int out_size, void* d_ws, size_t ws_size,
                              hipStream_t stream) {
    const float* logits = (const float*)d_in[0];   // (64,300,2)
    const float* boxes  = (const float*)d_in[1];   // (64,300,4)
    const float* tgt    = (const float*)d_in[2];   // (1024,4)
    float* out = (float*)d_out;

    cost_kernel<<<dim3(BS*NQ), 256, 0, stream>>>(logits, boxes, tgt, out);
    hung_kernel<<<dim3(BS), 64, 0, stream>>>(out, out);
}

// Round 9
// 39.872 us; speedup vs baseline: 1.4253x; 1.4253x over previous
//
#include <hip/hip_runtime.h>

#define BS 64
#define NQ 300
#define NTGT 1024
#define TT 16
#define MCOL 300
#define NROW 16
#define STR 304
#define BIGF 1000000000.0f

// ---- shared per-cell cost (identical formula in both paths) ----
__device__ __forceinline__ float cell_cost(float p0, float pcx, float pcy, float pw, float ph,
                                           float px1, float py1, float px2, float py2, float parea,
                                           float4 tb)
{
    float cb = fabsf(pcx - tb.x) + fabsf(pcy - tb.y) + fabsf(pw - tb.z) + fabsf(ph - tb.w);
    float tx1 = tb.x - 0.5f*tb.z, ty1 = tb.y - 0.5f*tb.w;
    float tx2 = tb.x + 0.5f*tb.z, ty2 = tb.y + 0.5f*tb.w;
    float tarea = (tx2 - tx1) * (ty2 - ty1);
    float ltx = fmaxf(px1, tx1), lty = fmaxf(py1, ty1);
    float rbx = fminf(px2, tx2), rby = fminf(py2, ty2);
    float iw = fmaxf(rbx - ltx, 0.f), ih = fmaxf(rby - lty, 0.f);
    float inter = iw * ih;
    float uni = parea + tarea - inter;
    float iou = inter * __builtin_amdgcn_rcpf(uni);
    float ex1 = fminf(px1, tx1), ey1 = fminf(py1, ty1);
    float ex2 = fmaxf(px2, tx2), ey2 = fmaxf(py2, ty2);
    float areae = (ex2 - ex1) * (ey2 - ey1);
    float giou = iou - (areae - uni) * __builtin_amdgcn_rcpf(areae);
    return cb - giou - p0;
}

// ---- DPP wave-64 min reductions (result valid in lane 63) ----
template<int CTRL>
__device__ __forceinline__ float dppmin_f(float x) {
    int t = __builtin_amdgcn_update_dpp(__float_as_int(BIGF), __float_as_int(x),
                                        CTRL, 0xF, 0xF, false);
    return fminf(x, __int_as_float(t));
}
template<int CTRL>
__device__ __forceinline__ int dppmin_i(int x) {
    int t = __builtin_amdgcn_update_dpp(0x7FFFFFFF, x, CTRL, 0xF, 0xF, false);
    return (t < x) ? t : x;
}
__device__ __forceinline__ float wave_min_f(float x) {
    x = dppmin_f<0x111>(x);  // row_shr:1
    x = dppmin_f<0x112>(x);  // row_shr:2
    x = dppmin_f<0x114>(x);  // row_shr:4
    x = dppmin_f<0x118>(x);  // row_shr:8
    x = dppmin_f<0x142>(x);  // row_bcast:15
    x = dppmin_f<0x143>(x);  // row_bcast:31
    return x;
}
__device__ __forceinline__ int wave_min_i(int x) {
    x = dppmin_i<0x111>(x);
    x = dppmin_i<0x112>(x);
    x = dppmin_i<0x114>(x);
    x = dppmin_i<0x118>(x);
    x = dppmin_i<0x142>(x);
    x = dppmin_i<0x143>(x);
    return x;
}

// static-index select chain over 5 regs (k0 wave-uniform)
__device__ __forceinline__ int sel5i(const int a[5], int k0) {
    int r = a[0];
    r = (k0 == 1) ? a[1] : r;
    r = (k0 == 2) ? a[2] : r;
    r = (k0 == 3) ? a[3] : r;
    r = (k0 == 4) ? a[4] : r;
    return r;
}

// __launch_bounds__(256, 8): force VGPR <= 64 so the 19200 cost blocks keep
// 8 waves/SIMD. Any spill hits only the 64 warm-started JV waves (~20 iters).
__global__ __launch_bounds__(256, 8) void fused_kernel(
    const float* __restrict__ logits,
    const float* __restrict__ boxes,
    const float* __restrict__ tgt,
    float* __restrict__ out)
{
    __shared__ float ca[16 * STR + 32];
    const int tid = threadIdx.x;

    if (blockIdx.x >= BS) {
        // ================= cost-matrix path: one q per block, 4 t per thread ==========
        int q = blockIdx.x - BS;                     // 0..19199, uniform per block
        float l0v = logits[2*q], l1v = logits[2*q + 1];
        float p0 = __builtin_amdgcn_rcpf(1.f + __expf(l1v - l0v));   // softmax[0]
        float4 pb = ((const float4*)boxes)[q];
        float px1 = pb.x - 0.5f*pb.z, py1 = pb.y - 0.5f*pb.w;
        float px2 = pb.x + 0.5f*pb.z, py2 = pb.y + 0.5f*pb.w;
        float parea = (px2 - px1) * (py2 - py1);

        int t0 = tid << 2;
        const float4* tgt4 = (const float4*)tgt;
        float4 tb0 = tgt4[t0+0], tb1 = tgt4[t0+1], tb2 = tgt4[t0+2], tb3 = tgt4[t0+3];
        float4 r;
        r.x = cell_cost(p0, pb.x, pb.y, pb.z, pb.w, px1, py1, px2, py2, parea, tb0);
        r.y = cell_cost(p0, pb.x, pb.y, pb.z, pb.w, px1, py1, px2, py2, parea, tb1);
        r.z = cell_cost(p0, pb.x, pb.y, pb.z, pb.w, px1, py1, px2, py2, parea, tb2);
        r.w = cell_cost(p0, pb.x, pb.y, pb.z, pb.w, px1, py1, px2, py2, parea, tb3);
        *(float4*)(out + (size_t)q * NTGT + t0) = r;
        return;
    }

    // ================= hungarian path: block b handles batch b =======================
    const int b = blockIdx.x;

    {
        auto fill_row = [&](int q) {
            float l0v = logits[(b*NQ + q)*2 + 0], l1v = logits[(b*NQ + q)*2 + 1];
            float p0 = __builtin_amdgcn_rcpf(1.f + __expf(l1v - l0v));
            float4 pb = ((const float4*)boxes)[b*NQ + q];
            float px1 = pb.x - 0.5f*pb.z, py1 = pb.y - 0.5f*pb.w;
            float px2 = pb.x + 0.5f*pb.z, py2 = pb.y + 0.5f*pb.w;
            float parea = (px2 - px1) * (py2 - py1);
            #pragma unroll
            for (int t = 0; t < TT; ++t) {
                float4 tb = ((const float4*)tgt)[b*TT + t];
                ca[t*STR + 1 + q] =
                    cell_cost(p0, pb.x, pb.y, pb.z, pb.w, px1, py1, px2, py2, parea, tb);
            }
        };
        fill_row(tid);                      // q = 0..255
        if (tid >= 212) fill_row(tid + 44); // q = 256..299
        if (tid < 16) ca[tid*STR] = 0.f;    // dummy col 0
    }
    __syncthreads();
    if (tid >= 64) return;                  // wave 0 runs JV, barrier-free

    __builtin_amdgcn_s_setprio(1);

    // ---- register-only JV shortest-augmenting-path, ROW-SIDE warm start ----
    // u[i] = rowmin_i, v = 0: feasible potential => exact optimum (same as ref).
    const int lane = tid;

    // rowmin_i stored in lane i (i=1..16). Rolled loop: keep live registers low.
    float u_lane = 0.f;
    #pragma unroll 1
    for (int t = 0; t < 16; ++t) {
        float loc = BIGF;
        #pragma unroll
        for (int k = 0; k < 5; ++k) {
            int j = lane + (k << 6);
            float c = ca[t*STR + j];
            bool ok = (j >= 1) && (j <= MCOL);
            loc = fminf(loc, ok ? c : BIGF);
        }
        float rm = __int_as_float(
            __builtin_amdgcn_readlane(__float_as_int(wave_min_f(loc)), 63));
        if (lane == t + 1) u_lane = rm;
    }

    int   p_reg[5]   = {0,0,0,0,0};
    int   way_reg[5] = {0,0,0,0,0};
    float vloc[5]    = {0.f,0.f,0.f,0.f,0.f};
    float minv[5];

    for (int i = 1; i <= NROW; ++i) {
        if (lane == 0) p_reg[0] = i;
        unsigned usedm = 0, treemask = 0;
        #pragma unroll
        for (int k = 0; k < 5; ++k) { minv[k] = BIGF; way_reg[k] = 0; }

        int j0 = 0;
        for (;;) {
            int l0 = j0 & 63, k0 = j0 >> 6;            // uniform (SGPR)
            int i0 = __builtin_amdgcn_readlane(sel5i(p_reg, k0), l0);
            if (i0 == 0) break;
            float ui0 = __int_as_float(
                __builtin_amdgcn_readlane(__float_as_int(u_lane), i0));  // u[i0]
            if (lane == l0) usedm |= (1u << k0);
            treemask |= (1u << i0);                     // uniform

            int rowbase = (i0 - 1) * STR + lane;
            float cur[5];
            #pragma unroll
            for (int k = 0; k < 5; ++k) cur[k] = ca[rowbase + (k << 6)];

            float bestv = BIGF; int bestj = 0x7FFFFFFF;
            #pragma unroll
            for (int k = 0; k < 5; ++k) {
                int j = lane + (k << 6);
                bool act = (j <= MCOL);
                bool us  = ((usedm >> k) & 1u) != 0u;
                float cu = cur[k] - ui0 - vloc[k];
                if (act && !us && cu < minv[k]) { minv[k] = cu; way_reg[k] = j0; }
                float mk = (act && !us) ? minv[k] : BIGF;
                if (mk < bestv) { bestv = mk; bestj = j; }  // ascending j per lane
            }
            // wave argmin: DPP value-min, broadcast, then DPP index-min among equals
            float mv = wave_min_f(bestv);
            float delta = __int_as_float(__builtin_amdgcn_readlane(__float_as_int(mv), 63));
            int cand = (bestv == delta) ? bestj : 0x7FFFFFFF;
            int cm = wave_min_i(cand);
            int j1 = __builtin_amdgcn_readlane(cm, 63);

            #pragma unroll
            for (int k = 0; k < 5; ++k) {
                bool us = ((usedm >> k) & 1u) != 0u;
                if (us) { vloc[k] -= delta; }
                else if (lane + (k << 6) <= MCOL) minv[k] -= delta;
            }
            if (lane <= NROW && ((treemask >> lane) & 1u)) u_lane += delta;
            j0 = j1;
        }
        // augment: p[j0] = p[way[j0]] walking back to col 0 (uniform readlanes)
        while (j0 != 0) {
            int l0 = j0 & 63, k0 = j0 >> 6;
            int jn = __builtin_amdgcn_readlane(sel5i(way_reg, k0), l0);
            int pn = __builtin_amdgcn_readlane(sel5i(p_reg, jn >> 6), jn & 63);
            #pragma unroll
            for (int k = 0; k < 5; ++k)
                if (k == k0 && lane == l0) p_reg[k] = pn;
            j0 = jn;
        }
    }

    __builtin_amdgcn_s_setprio(0);

    // ---- extraction: row_ind/col_ind in ascending query order ----
    const size_t ROWB = (size_t)BS * NQ * NTGT;
    const size_t COLB = ROWB + (size_t)BS * TT;
    int base = 0;
    #pragma unroll
    for (int k = 0; k < 5; ++k) {
        int pk1 = (k < 4) ? __shfl(p_reg[k + 1], 0, 64) : 0;   // p[64(k+1)]
        int psh = __shfl(p_reg[k], (lane + 1) & 63, 64);       // p[64k + lane+1]
        int q = (k << 6) | lane;
        int a = (lane == 63) ? pk1 : psh;                      // = p[q+1]
        if (q >= MCOL) a = 0;
        unsigned long long mb = __ballot(a > 0);
        int pos = base + __popcll(mb & ((1ull << lane) - 1ull));
        if (a > 0) {
            out[ROWB + (size_t)b * TT + pos] = (float)q;
            out[COLB + (size_t)b * TT + pos] = (float)(a - 1);
        }
        base += __popcll(mb);
    }
}

extern "C" void kernel_launch(void* const* d_in, const int* in_sizes, int n_in,
                              void* d_out, int out_size, void* d_ws, size_t ws_size,
                              hipStream_t stream) {
    const float* logits = (const float*)d_in[0];   // (64,300,2)
    const float* boxes  = (const float*)d_in[1];   // (64,300,4)
    const float* tgt    = (const float*)d_in[2];   // (1024,4)
    float* out = (float*)d_out;

    // blocks 0..63: hungarian (self-contained); blocks 64..19263: cost matrix (1 q each)
    fused_kernel<<<dim3(BS + BS*NQ), 256, 0, stream>>>(logits, boxes, tgt, out);
}

// Round 10
// 33.138 us; speedup vs baseline: 1.7150x; 1.2032x over previous
//
#include <hip/hip_runtime.h>

#define BS 64
#define NQ 300
#define NTGT 1024
#define TT 16
#define MCOL 300
#define NROW 16
#define STR 304
#define BIGF 1000000000.0f

// ---- shared per-cell cost (identical formula in both paths) ----
__device__ __forceinline__ float cell_cost(float p0, float pcx, float pcy, float pw, float ph,
                                           float px1, float py1, float px2, float py2, float parea,
                                           float4 tb)
{
    float cb = fabsf(pcx - tb.x) + fabsf(pcy - tb.y) + fabsf(pw - tb.z) + fabsf(ph - tb.w);
    float tx1 = tb.x - 0.5f*tb.z, ty1 = tb.y - 0.5f*tb.w;
    float tx2 = tb.x + 0.5f*tb.z, ty2 = tb.y + 0.5f*tb.w;
    float tarea = (tx2 - tx1) * (ty2 - ty1);
    float ltx = fmaxf(px1, tx1), lty = fmaxf(py1, ty1);
    float rbx = fminf(px2, tx2), rby = fminf(py2, ty2);
    float iw = fmaxf(rbx - ltx, 0.f), ih = fmaxf(rby - lty, 0.f);
    float inter = iw * ih;
    float uni = parea + tarea - inter;
    float iou = inter * __builtin_amdgcn_rcpf(uni);
    float ex1 = fminf(px1, tx1), ey1 = fminf(py1, ty1);
    float ex2 = fmaxf(px2, tx2), ey2 = fmaxf(py2, ty2);
    float areae = (ex2 - ex1) * (ey2 - ey1);
    float giou = iou - (areae - uni) * __builtin_amdgcn_rcpf(areae);
    return cb - giou - p0;
}

// ---- DPP wave-64 min reductions (result valid in lane 63) ----
template<int CTRL>
__device__ __forceinline__ float dppmin_f(float x) {
    int t = __builtin_amdgcn_update_dpp(__float_as_int(BIGF), __float_as_int(x),
                                        CTRL, 0xF, 0xF, false);
    return fminf(x, __int_as_float(t));
}
template<int CTRL>
__device__ __forceinline__ int dppmin_i(int x) {
    int t = __builtin_amdgcn_update_dpp(0x7FFFFFFF, x, CTRL, 0xF, 0xF, false);
    return (t < x) ? t : x;
}
__device__ __forceinline__ float wave_min_f(float x) {
    x = dppmin_f<0x111>(x);  // row_shr:1
    x = dppmin_f<0x112>(x);  // row_shr:2
    x = dppmin_f<0x114>(x);  // row_shr:4
    x = dppmin_f<0x118>(x);  // row_shr:8
    x = dppmin_f<0x142>(x);  // row_bcast:15
    x = dppmin_f<0x143>(x);  // row_bcast:31
    return x;
}
__device__ __forceinline__ int wave_min_i(int x) {
    x = dppmin_i<0x111>(x);
    x = dppmin_i<0x112>(x);
    x = dppmin_i<0x114>(x);
    x = dppmin_i<0x118>(x);
    x = dppmin_i<0x142>(x);
    x = dppmin_i<0x143>(x);
    return x;
}

// ---- uniform-index gather from a 5-reg distributed array via v_readlane ----
__device__ __forceinline__ int rl5(const int a[5], int k0, int l0) {
    int r0 = __builtin_amdgcn_readlane(a[0], l0);
    int r1 = __builtin_amdgcn_readlane(a[1], l0);
    int r2 = __builtin_amdgcn_readlane(a[2], l0);
    int r3 = __builtin_amdgcn_readlane(a[3], l0);
    int r4 = __builtin_amdgcn_readlane(a[4], l0);
    int r = r0;
    r = (k0 == 1) ? r1 : r;
    r = (k0 == 2) ? r2 : r;
    r = (k0 == 3) ? r3 : r;
    r = (k0 == 4) ? r4 : r;
    return r;
}
__device__ __forceinline__ float rl5f(const float a[5], int k0, int l0) {
    int ai[5] = { __float_as_int(a[0]), __float_as_int(a[1]), __float_as_int(a[2]),
                  __float_as_int(a[3]), __float_as_int(a[4]) };
    return __int_as_float(rl5(ai, k0, l0));
}

__global__ __launch_bounds__(256) void fused_kernel(
    const float* __restrict__ logits,
    const float* __restrict__ boxes,
    const float* __restrict__ tgt,
    float* __restrict__ out)
{
    __shared__ float ca[16 * STR + 32];
    const int tid = threadIdx.x;

    if (blockIdx.x >= BS) {
        // ================= cost-matrix path: one q per block, 4 t per thread ==========
        int q = blockIdx.x - BS;                     // 0..19199, uniform per block
        float l0v = logits[2*q], l1v = logits[2*q + 1];
        float p0 = __builtin_amdgcn_rcpf(1.f + __expf(l1v - l0v));   // softmax[0]
        float4 pb = ((const float4*)boxes)[q];
        float px1 = pb.x - 0.5f*pb.z, py1 = pb.y - 0.5f*pb.w;
        float px2 = pb.x + 0.5f*pb.z, py2 = pb.y + 0.5f*pb.w;
        float parea = (px2 - px1) * (py2 - py1);

        int t0 = tid << 2;
        const float4* tgt4 = (const float4*)tgt;
        float4 tb0 = tgt4[t0+0], tb1 = tgt4[t0+1], tb2 = tgt4[t0+2], tb3 = tgt4[t0+3];
        float4 r;
        r.x = cell_cost(p0, pb.x, pb.y, pb.z, pb.w, px1, py1, px2, py2, parea, tb0);
        r.y = cell_cost(p0, pb.x, pb.y, pb.z, pb.w, px1, py1, px2, py2, parea, tb1);
        r.z = cell_cost(p0, pb.x, pb.y, pb.z, pb.w, px1, py1, px2, py2, parea, tb2);
        r.w = cell_cost(p0, pb.x, pb.y, pb.z, pb.w, px1, py1, px2, py2, parea, tb3);
        *(float4*)(out + (size_t)q * NTGT + t0) = r;
        return;
    }

    // ================= hungarian path: block b handles batch b =======================
    const int b = blockIdx.x;

    {
        auto fill_row = [&](int q) {
            float l0v = logits[(b*NQ + q)*2 + 0], l1v = logits[(b*NQ + q)*2 + 1];
            float p0 = __builtin_amdgcn_rcpf(1.f + __expf(l1v - l0v));
            float4 pb = ((const float4*)boxes)[b*NQ + q];
            float px1 = pb.x - 0.5f*pb.z, py1 = pb.y - 0.5f*pb.w;
            float px2 = pb.x + 0.5f*pb.z, py2 = pb.y + 0.5f*pb.w;
            float parea = (px2 - px1) * (py2 - py1);
            #pragma unroll
            for (int t = 0; t < TT; ++t) {
                float4 tb = ((const float4*)tgt)[b*TT + t];
                ca[t*STR + 1 + q] =
                    cell_cost(p0, pb.x, pb.y, pb.z, pb.w, px1, py1, px2, py2, parea, tb);
            }
        };
        fill_row(tid);                      // q = 0..255
        if (tid >= 212) fill_row(tid + 44); // q = 256..299
        if (tid < 16) ca[tid*STR] = 0.f;    // dummy col 0
    }
    __syncthreads();
    if (tid >= 64) return;                  // wave 0 runs JV, barrier-free

    __builtin_amdgcn_s_setprio(1);

    // ---- register-only JV shortest-augmenting-path (R3 body, verbatim) ----
    const int lane = tid;

    // WARM START (only change vs R3): u[i] = rowmin_i, v = 0 — feasible potential,
    // exact optimum; cuts Dijkstra bodies ~136 -> ~20. Rolled to keep VGPR low.
    float u_lane = 0.f;
    #pragma unroll 1
    for (int t = 0; t < 16; ++t) {
        float loc = BIGF;
        #pragma unroll
        for (int k = 0; k < 5; ++k) {
            int j = lane + (k << 6);
            float c = ca[t*STR + j];
            loc = fminf(loc, (j >= 1 && j <= MCOL) ? c : BIGF);
        }
        float rm = __int_as_float(
            __builtin_amdgcn_readlane(__float_as_int(wave_min_f(loc)), 63));
        u_lane = (lane == t + 1) ? rm : u_lane;
    }

    int   p_reg[5]   = {0,0,0,0,0};
    int   way_reg[5] = {0,0,0,0,0};
    float vloc[5]    = {0.f,0.f,0.f,0.f,0.f};
    float minv[5], ur_reg[5];

    for (int i = 1; i <= NROW; ++i) {
        if (lane == 0) p_reg[0] = i;
        unsigned usedm = 0, treemask = 0;
        #pragma unroll
        for (int k = 0; k < 5; ++k) { minv[k] = BIGF; way_reg[k] = 0; }
        #pragma unroll
        for (int k = 0; k < 5; ++k) ur_reg[k] = __shfl(u_lane, p_reg[k], 64); // u[p[j]]

        int j0 = 0;
        for (;;) {
            int l0 = j0 & 63, k0 = j0 >> 6;            // uniform (SGPR)
            int i0 = rl5(p_reg, k0, l0);
            if (i0 == 0) break;
            float ui0 = rl5f(ur_reg, k0, l0);
            if (lane == l0) usedm |= (1u << k0);
            treemask |= (1u << i0);                     // uniform

            int rowbase = (i0 - 1) * STR + lane;
            float cur[5];
            #pragma unroll
            for (int k = 0; k < 5; ++k) cur[k] = ca[rowbase + (k << 6)];

            float bestv = BIGF; int bestj = 0x7FFFFFFF;
            #pragma unroll
            for (int k = 0; k < 5; ++k) {
                int j = lane + (k << 6);
                bool act = (j <= MCOL);
                bool us  = ((usedm >> k) & 1u) != 0u;
                float cu = cur[k] - ui0 - vloc[k];
                if (act && !us && cu < minv[k]) { minv[k] = cu; way_reg[k] = j0; }
                float mk = (act && !us) ? minv[k] : BIGF;
                if (mk < bestv) { bestv = mk; bestj = j; }  // ascending j per lane
            }
            // wave argmin: DPP value-min, broadcast, then DPP index-min among equals
            float mv = wave_min_f(bestv);
            float delta = __int_as_float(__builtin_amdgcn_readlane(__float_as_int(mv), 63));
            int cand = (bestv == delta) ? bestj : 0x7FFFFFFF;
            int cm = wave_min_i(cand);
            int j1 = __builtin_amdgcn_readlane(cm, 63);

            #pragma unroll
            for (int k = 0; k < 5; ++k) {
                bool us = ((usedm >> k) & 1u) != 0u;
                if (us) { vloc[k] -= delta; ur_reg[k] += delta; }
                else if (lane + (k << 6) <= MCOL) minv[k] -= delta;
            }
            if (lane <= NROW && ((treemask >> lane) & 1u)) u_lane += delta;
            j0 = j1;
        }
        // augment: p[j0] = p[way[j0]] walking back to col 0 (uniform readlanes)
        while (j0 != 0) {
            int l0 = j0 & 63, k0 = j0 >> 6;
            int jn = rl5(way_reg, k0, l0);
            int pn = rl5(p_reg, jn >> 6, jn & 63);
            #pragma unroll
            for (int k = 0; k < 5; ++k)
                if (k == k0 && lane == l0) p_reg[k] = pn;
            j0 = jn;
        }
    }

    __builtin_amdgcn_s_setprio(0);

    // ---- extraction: row_ind/col_ind in ascending query order ----
    const size_t ROWB = (size_t)BS * NQ * NTGT;
    const size_t COLB = ROWB + (size_t)BS * TT;
    int base = 0;
    #pragma unroll
    for (int k = 0; k < 5; ++k) {
        int pk1 = (k < 4) ? __shfl(p_reg[k + 1], 0, 64) : 0;   // p[64(k+1)]
        int psh = __shfl(p_reg[k], (lane + 1) & 63, 64);       // p[64k + lane+1]
        int q = (k << 6) | lane;
        int a = (lane == 63) ? pk1 : psh;                      // = p[q+1]
        if (q >= MCOL) a = 0;
        unsigned long long mb = __ballot(a > 0);
        int pos = base + __popcll(mb & ((1ull << lane) - 1ull));
        if (a > 0) {
            out[ROWB + (size_t)b * TT + pos] = (float)q;
            out[COLB + (size_t)b * TT + pos] = (float)(a - 1);
        }
        base += __popcll(mb);
    }
}

extern "C" void kernel_launch(void* const* d_in, const int* in_sizes, int n_in,
                              void* d_out, int out_size, void* d_ws, size_t ws_size,
                              hipStream_t stream) {
    const float* logits = (const float*)d_in[0];   // (64,300,2)
    const float* boxes  = (const float*)d_in[1];   // (64,300,4)
    const float* tgt    = (const float*)d_in[2];   // (1024,4)
    float* out = (float*)d_out;

    // blocks 0..63: hungarian (self-contained); blocks 64..19263: cost matrix (1 q each)
    fused_kernel<<<dim3(BS + BS*NQ), 256, 0, stream>>>(logits, boxes, tgt, out);
}

// Round 11
// 32.485 us; speedup vs baseline: 1.7494x; 1.0201x over previous
//
#include <hip/hip_runtime.h>

#define BS 64
#define NQ 300
#define NTGT 1024
#define TT 16
#define MCOL 300
#define NROW 16
#define STR 304
#define BIGF 1000000000.0f
#define CQBLK 2048   // persistent cost blocks

// ---- DPP wave-64 min reductions (result valid in lane 63) ----
template<int CTRL>
__device__ __forceinline__ float dppmin_f(float x) {
    int t = __builtin_amdgcn_update_dpp(__float_as_int(BIGF), __float_as_int(x),
                                        CTRL, 0xF, 0xF, false);
    return fminf(x, __int_as_float(t));
}
template<int CTRL>
__device__ __forceinline__ int dppmin_i(int x) {
    int t = __builtin_amdgcn_update_dpp(0x7FFFFFFF, x, CTRL, 0xF, 0xF, false);
    return (t < x) ? t : x;
}
__device__ __forceinline__ float wave_min_f(float x) {
    x = dppmin_f<0x111>(x);  // row_shr:1
    x = dppmin_f<0x112>(x);  // row_shr:2
    x = dppmin_f<0x114>(x);  // row_shr:4
    x = dppmin_f<0x118>(x);  // row_shr:8
    x = dppmin_f<0x142>(x);  // row_bcast:15
    x = dppmin_f<0x143>(x);  // row_bcast:31
    return x;
}
__device__ __forceinline__ int wave_min_i(int x) {
    x = dppmin_i<0x111>(x);
    x = dppmin_i<0x112>(x);
    x = dppmin_i<0x114>(x);
    x = dppmin_i<0x118>(x);
    x = dppmin_i<0x142>(x);
    x = dppmin_i<0x143>(x);
    return x;
}

// ---- uniform-index gather from a 5-reg distributed array via v_readlane ----
__device__ __forceinline__ int rl5(const int a[5], int k0, int l0) {
    int r0 = __builtin_amdgcn_readlane(a[0], l0);
    int r1 = __builtin_amdgcn_readlane(a[1], l0);
    int r2 = __builtin_amdgcn_readlane(a[2], l0);
    int r3 = __builtin_amdgcn_readlane(a[3], l0);
    int r4 = __builtin_amdgcn_readlane(a[4], l0);
    int r = r0;
    r = (k0 == 1) ? r1 : r;
    r = (k0 == 2) ? r2 : r;
    r = (k0 == 3) ? r3 : r;
    r = (k0 == 4) ? r4 : r;
    return r;
}
__device__ __forceinline__ float rl5f(const float a[5], int k0, int l0) {
    int ai[5] = { __float_as_int(a[0]), __float_as_int(a[1]), __float_as_int(a[2]),
                  __float_as_int(a[3]), __float_as_int(a[4]) };
    return __int_as_float(rl5(ai, k0, l0));
}

// ---- per-cell cost given pre-converted pred and target (bit-identical math) ----
__device__ __forceinline__ float cell_cost_pc(
    float p0, float4 pb, float px1, float py1, float px2, float py2, float parea,
    float4 tb, float tx1, float ty1, float tx2, float ty2, float tarea)
{
    float cb = fabsf(pb.x - tb.x) + fabsf(pb.y - tb.y) + fabsf(pb.z - tb.z) + fabsf(pb.w - tb.w);
    float ltx = fmaxf(px1, tx1), lty = fmaxf(py1, ty1);
    float rbx = fminf(px2, tx2), rby = fminf(py2, ty2);
    float iw = fmaxf(rbx - ltx, 0.f), ih = fmaxf(rby - lty, 0.f);
    float inter = iw * ih;
    float uni = parea + tarea - inter;
    float iou = inter * __builtin_amdgcn_rcpf(uni);
    float ex1 = fminf(px1, tx1), ey1 = fminf(py1, ty1);
    float ex2 = fmaxf(px2, tx2), ey2 = fmaxf(py2, ty2);
    float areae = (ex2 - ex1) * (ey2 - ey1);
    float giou = iou - (areae - uni) * __builtin_amdgcn_rcpf(areae);
    return cb - giou - p0;
}

__global__ __launch_bounds__(256) void fused_kernel(
    const float* __restrict__ logits,
    const float* __restrict__ boxes,
    const float* __restrict__ tgt,
    float* __restrict__ out)
{
    __shared__ float ca[16 * STR + 32];
    const int tid = threadIdx.x;

    if (blockIdx.x >= BS) {
        // ========== cost path: persistent blocks, targets cached in registers ==========
        int cbid = blockIdx.x - BS;                  // 0..2047
        int t0 = tid << 2;
        const float4* tgt4 = (const float4*)tgt;

        // convert this thread's 4 targets ONCE
        float4 tb0 = tgt4[t0+0], tb1 = tgt4[t0+1], tb2 = tgt4[t0+2], tb3 = tgt4[t0+3];
        float ax1[4], ay1[4], ax2[4], ay2[4], aar[4];
        {
            float4 tt;
            tt = tb0; ax1[0]=tt.x-0.5f*tt.z; ay1[0]=tt.y-0.5f*tt.w; ax2[0]=tt.x+0.5f*tt.z; ay2[0]=tt.y+0.5f*tt.w; aar[0]=(ax2[0]-ax1[0])*(ay2[0]-ay1[0]);
            tt = tb1; ax1[1]=tt.x-0.5f*tt.z; ay1[1]=tt.y-0.5f*tt.w; ax2[1]=tt.x+0.5f*tt.z; ay2[1]=tt.y+0.5f*tt.w; aar[1]=(ax2[1]-ax1[1])*(ay2[1]-ay1[1]);
            tt = tb2; ax1[2]=tt.x-0.5f*tt.z; ay1[2]=tt.y-0.5f*tt.w; ax2[2]=tt.x+0.5f*tt.z; ay2[2]=tt.y+0.5f*tt.w; aar[2]=(ax2[2]-ax1[2])*(ay2[2]-ay1[2]);
            tt = tb3; ax1[3]=tt.x-0.5f*tt.z; ay1[3]=tt.y-0.5f*tt.w; ax2[3]=tt.x+0.5f*tt.z; ay2[3]=tt.y+0.5f*tt.w; aar[3]=(ax2[3]-ax1[3])*(ay2[3]-ay1[3]);
        }

        const float2* lg2 = (const float2*)logits;
        const float4* bx4 = (const float4*)boxes;
        for (int q = cbid; q < BS * NQ; q += CQBLK) {
            float2 lg = lg2[q];
            float p0 = __builtin_amdgcn_rcpf(1.f + __expf(lg.y - lg.x));  // softmax[0]
            float4 pb = bx4[q];
            float px1 = pb.x - 0.5f*pb.z, py1 = pb.y - 0.5f*pb.w;
            float px2 = pb.x + 0.5f*pb.z, py2 = pb.y + 0.5f*pb.w;
            float parea = (px2 - px1) * (py2 - py1);

            float4 r;
            r.x = cell_cost_pc(p0, pb, px1, py1, px2, py2, parea, tb0, ax1[0], ay1[0], ax2[0], ay2[0], aar[0]);
            r.y = cell_cost_pc(p0, pb, px1, py1, px2, py2, parea, tb1, ax1[1], ay1[1], ax2[1], ay2[1], aar[1]);
            r.z = cell_cost_pc(p0, pb, px1, py1, px2, py2, parea, tb2, ax1[2], ay1[2], ax2[2], ay2[2], aar[2]);
            r.w = cell_cost_pc(p0, pb, px1, py1, px2, py2, parea, tb3, ax1[3], ay1[3], ax2[3], ay2[3], aar[3]);
            *(float4*)(out + (size_t)q * NTGT + t0) = r;
        }
        return;
    }

    // ================= hungarian path (R10 verbatim): block b = batch b ==============
    const int b = blockIdx.x;

    {
        auto fill_row = [&](int q) {
            float l0v = logits[(b*NQ + q)*2 + 0], l1v = logits[(b*NQ + q)*2 + 1];
            float p0 = __builtin_amdgcn_rcpf(1.f + __expf(l1v - l0v));
            float4 pb = ((const float4*)boxes)[b*NQ + q];
            float px1 = pb.x - 0.5f*pb.z, py1 = pb.y - 0.5f*pb.w;
            float px2 = pb.x + 0.5f*pb.z, py2 = pb.y + 0.5f*pb.w;
            float parea = (px2 - px1) * (py2 - py1);
            #pragma unroll
            for (int t = 0; t < TT; ++t) {
                float4 tb = ((const float4*)tgt)[b*TT + t];
                float tx1 = tb.x - 0.5f*tb.z, ty1 = tb.y - 0.5f*tb.w;
                float tx2 = tb.x + 0.5f*tb.z, ty2 = tb.y + 0.5f*tb.w;
                float tarea = (tx2 - tx1) * (ty2 - ty1);
                ca[t*STR + 1 + q] = cell_cost_pc(p0, pb, px1, py1, px2, py2, parea,
                                                 tb, tx1, ty1, tx2, ty2, tarea);
            }
        };
        fill_row(tid);                      // q = 0..255
        if (tid >= 212) fill_row(tid + 44); // q = 256..299
        if (tid < 16) ca[tid*STR] = 0.f;    // dummy col 0
    }
    __syncthreads();
    if (tid >= 64) return;                  // wave 0 runs JV, barrier-free

    __builtin_amdgcn_s_setprio(1);

    const int lane = tid;

    // WARM START: u[i] = rowmin_i, v = 0 — feasible potential, exact optimum.
    float u_lane = 0.f;
    #pragma unroll 1
    for (int t = 0; t < 16; ++t) {
        float loc = BIGF;
        #pragma unroll
        for (int k = 0; k < 5; ++k) {
            int j = lane + (k << 6);
            float c = ca[t*STR + j];
            loc = fminf(loc, (j >= 1 && j <= MCOL) ? c : BIGF);
        }
        float rm = __int_as_float(
            __builtin_amdgcn_readlane(__float_as_int(wave_min_f(loc)), 63));
        u_lane = (lane == t + 1) ? rm : u_lane;
    }

    int   p_reg[5]   = {0,0,0,0,0};
    int   way_reg[5] = {0,0,0,0,0};
    float vloc[5]    = {0.f,0.f,0.f,0.f,0.f};
    float minv[5], ur_reg[5];

    for (int i = 1; i <= NROW; ++i) {
        if (lane == 0) p_reg[0] = i;
        unsigned usedm = 0, treemask = 0;
        #pragma unroll
        for (int k = 0; k < 5; ++k) { minv[k] = BIGF; way_reg[k] = 0; }
        #pragma unroll
        for (int k = 0; k < 5; ++k) ur_reg[k] = __shfl(u_lane, p_reg[k], 64); // u[p[j]]

        int j0 = 0;
        for (;;) {
            int l0 = j0 & 63, k0 = j0 >> 6;            // uniform (SGPR)
            int i0 = rl5(p_reg, k0, l0);
            if (i0 == 0) break;
            float ui0 = rl5f(ur_reg, k0, l0);
            if (lane == l0) usedm |= (1u << k0);
            treemask |= (1u << i0);                     // uniform

            int rowbase = (i0 - 1) * STR + lane;
            float cur[5];
            #pragma unroll
            for (int k = 0; k < 5; ++k) cur[k] = ca[rowbase + (k << 6)];

            float bestv = BIGF; int bestj = 0x7FFFFFFF;
            #pragma unroll
            for (int k = 0; k < 5; ++k) {
                int j = lane + (k << 6);
                bool act = (j <= MCOL);
                bool us  = ((usedm >> k) & 1u) != 0u;
                float cu = cur[k] - ui0 - vloc[k];
                if (act && !us && cu < minv[k]) { minv[k] = cu; way_reg[k] = j0; }
                float mk = (act && !us) ? minv[k] : BIGF;
                if (mk < bestv) { bestv = mk; bestj = j; }  // ascending j per lane
            }
            // wave argmin: DPP value-min, broadcast, then DPP index-min among equals
            float mv = wave_min_f(bestv);
            float delta = __int_as_float(__builtin_amdgcn_readlane(__float_as_int(mv), 63));
            int cand = (bestv == delta) ? bestj : 0x7FFFFFFF;
            int cm = wave_min_i(cand);
            int j1 = __builtin_amdgcn_readlane(cm, 63);

            #pragma unroll
            for (int k = 0; k < 5; ++k) {
                bool us = ((usedm >> k) & 1u) != 0u;
                if (us) { vloc[k] -= delta; ur_reg[k] += delta; }
                else if (lane + (k << 6) <= MCOL) minv[k] -= delta;
            }
            if (lane <= NROW && ((treemask >> lane) & 1u)) u_lane += delta;
            j0 = j1;
        }
        // augment: p[j0] = p[way[j0]] walking back to col 0 (uniform readlanes)
        while (j0 != 0) {
            int l0 = j0 & 63, k0 = j0 >> 6;
            int jn = rl5(way_reg, k0, l0);
            int pn = rl5(p_reg, jn >> 6, jn & 63);
            #pragma unroll
            for (int k = 0; k < 5; ++k)
                if (k == k0 && lane == l0) p_reg[k] = pn;
            j0 = jn;
        }
    }

    __builtin_amdgcn_s_setprio(0);

    // ---- extraction: row_ind/col_ind in ascending query order ----
    const size_t ROWB = (size_t)BS * NQ * NTGT;
    const size_t COLB = ROWB + (size_t)BS * TT;
    int base = 0;
    #pragma unroll
    for (int k = 0; k < 5; ++k) {
        int pk1 = (k < 4) ? __shfl(p_reg[k + 1], 0, 64) : 0;   // p[64(k+1)]
        int psh = __shfl(p_reg[k], (lane + 1) & 63, 64);       // p[64k + lane+1]
        int q = (k << 6) | lane;
        int a = (lane == 63) ? pk1 : psh;                      // = p[q+1]
        if (q >= MCOL) a = 0;
        unsigned long long mb = __ballot(a > 0);
        int pos = base + __popcll(mb & ((1ull << lane) - 1ull));
        if (a > 0) {
            out[ROWB + (size_t)b * TT + pos] = (float)q;
            out[COLB + (size_t)b * TT + pos] = (float)(a - 1);
        }
        base += __popcll(mb);
    }
}

extern "C" void kernel_launch(void* const* d_in, const int* in_sizes, int n_in,
                              void* d_out, int out_size, void* d_ws, size_t ws_size,
                              hipStream_t stream) {
    const float* logits = (const float*)d_in[0];   // (64,300,2)
    const float* boxes  = (const float*)d_in[1];   // (64,300,4)
    const float* tgt    = (const float*)d_in[2];   // (1024,4)
    float* out = (float*)d_out;

    // blocks 0..63: hungarian; blocks 64..2111: persistent cost blocks
    fused_kernel<<<dim3(BS + CQBLK), 256, 0, stream>>>(logits, boxes, tgt, out);
}